// Round 4
// baseline (28.768 us; speedup 1.0000x reference)
//
#include <hip/hip_runtime.h>

static constexpr int HID = 64;
static constexpr int M   = 63;            // intervals; knots 0..63 = one wave
static constexpr int NK  = 64;
static constexpr int TPB = 256;
static constexpr int OVPT  = 8;           // outputs per thread
static constexpr int OTILE = TPB * OVPT;  // 2048 outputs per block

__device__ __forceinline__ float softplusf(float x) {
  return (x > 20.0f) ? x : log1pf(expf(x));
}

// Single fused kernel. Every block redundantly:
//  1. evaluates beta = softplus(MLP(t)) at 64 knots (LDS-staged layer-1,
//     W2 from L1, 1024 FMA/thread),
//  2. runs 7 Picard half-passes of the SIR integral equations entirely in
//     one wave's registers (lane p = knot p) with 4th-order cumulative
//     quadrature (shfl stencils + shfl_up scan, no LDS, no barriers),
//  3. cubic-interpolates Q_I and writes its own 2048-output slice.
// All blocks compute identical values; each output is written exactly once.
//   Qa = int beta*I du (S-exponent), Qb = int beta*S du (I-exponent)
//   S = S0*exp(-Qa) ; I = I0*exp(Qb - g*t)
__global__ void __launch_bounds__(TPB)
sir_fused_kernel(const float* __restrict__ I_init,
                 const float* __restrict__ W1, const float* __restrict__ b1,
                 const float* __restrict__ W2, const float* __restrict__ b2,
                 const float* __restrict__ W3, const float* __restrict__ b3,
                 const float* __restrict__ gamma_param,
                 float* __restrict__ out, int T) {
  __shared__ float h1T[HID * NK];   // [unit][knot], 16 KB, conflict-free
  __shared__ float beta_s[NK];

  const int tid  = threadIdx.x;
  const int lane = tid & 63;
  const int wid  = tid >> 6;

  const float I0 = I_init[0];
  const float S0 = 1.0f - I0;
  const float g  = softplusf(gamma_param[0]);
  const float h  = 1.0f / (float)M;

  // ---- layer 1: h1T[unit][knot] = tanh(t_knot * W1[unit] + b1[unit]) ----
  {
    float u = (float)lane * h;                    // knot = lane
#pragma unroll
    for (int r = 0; r < 16; ++r) {
      int unit = r * 4 + wid;                     // wave-uniform unit
      h1T[unit * NK + lane] = tanhf(fmaf(u, W1[unit], b1[unit]));
    }
  }
  __syncthreads();

  // ---- layers 2+3: thread -> (knot = tid>>2, 16 units j0..j0+15) ----
  {
    const int knot = tid >> 2;
    const int q    = tid & 3;
    const int j0   = q * 16;
    float z2[16];
#pragma unroll
    for (int c = 0; c < 4; ++c) {
      float4 b = *(const float4*)(b2 + j0 + 4 * c);
      z2[4*c+0] = b.x; z2[4*c+1] = b.y; z2[4*c+2] = b.z; z2[4*c+3] = b.w;
    }
    for (int k = 0; k < HID; ++k) {
      float hk = h1T[k * NK + knot];              // 16-addr broadcast, no conflict
      const float4* w4 = (const float4*)(W2 + k * HID + j0);
#pragma unroll
      for (int c = 0; c < 4; ++c) {
        float4 w = w4[c];
        z2[4*c+0] = fmaf(hk, w.x, z2[4*c+0]);
        z2[4*c+1] = fmaf(hk, w.y, z2[4*c+1]);
        z2[4*c+2] = fmaf(hk, w.z, z2[4*c+2]);
        z2[4*c+3] = fmaf(hk, w.w, z2[4*c+3]);
      }
    }
    float acc = 0.0f;
#pragma unroll
    for (int jj = 0; jj < 16; ++jj)
      acc = fmaf(tanhf(z2[jj]), W3[j0 + jj], acc);
    acc += __shfl_xor(acc, 1);
    acc += __shfl_xor(acc, 2);
    if (q == 0) beta_s[knot] = softplusf(acc + b3[0]);
  }
  __syncthreads();

  // ---- Picard: lane p = knot p; 7 half-passes, all in registers ----
  const int p = lane;
  const float tp = (float)p * h;
  const float bet = beta_s[p];
  const float c24 = h * (1.0f / 24.0f);
  float QA = 0.0f, QB = 0.0f;
  const int im2 = p >= 2 ? p - 2 : 0;
  const int im1 = p >= 1 ? p - 1 : 0;
  const int ip1 = p <= 62 ? p + 1 : 63;
  const int ip2 = p <= 61 ? p + 2 : 63;
  const int ip3 = p <= 60 ? p + 3 : 63;
#pragma unroll
  for (int ph = 0; ph < 7; ++ph) {
    const bool iPass = (ph & 1) == 0;
    float f = iPass ? (bet * S0 * __expf(-QA))
                    : (bet * I0 * __expf(QB - g * tp));
    float fm2 = __shfl(f, im2);
    float fm1 = __shfl(f, im1);
    float f1  = __shfl(f, ip1);
    float f2  = __shfl(f, ip2);
    float f3  = __shfl(f, ip3);
    float e;
    if (p == 0)       e = 9.0f*f + 19.0f*f1 - 5.0f*f2 + f3;     // AM start
    else if (p < 62)  e = 13.0f*(f + f1) - fm1 - f2;            // interior
    else if (p == 62) e = fm2 - 5.0f*fm1 + 19.0f*f + 9.0f*f1;   // AM end
    else              e = 0.0f;                                 // lane 63
    e *= c24;
    float incl = e;
#pragma unroll
    for (int off = 1; off < 64; off <<= 1) {
      float w = __shfl_up(incl, off);
      if (lane >= off) incl += w;
    }
    float Q = incl - e;                    // exclusive prefix = Q at knot p
    if (iPass) QB = Q; else QA = Q;
  }
  // QB (I-exponent) now lives in each wave's lanes.

  // ---- output slice: cubic-Lagrange interp of QB via lane-indexed shfl ----
  const float scale = (float)M / (float)T;
  int o0 = blockIdx.x * OTILE + tid * OVPT;
  float r[OVPT];
#pragma unroll
  for (int u = 0; u < OVPT; ++u) {
    int i = o0 + u;
    float pos = (float)(i + 1) * scale;            // (0, M]
    int js = (int)pos - 1;
    js = js < 0 ? 0 : (js > M - 3 ? M - 3 : js);   // [0, 60]
    float x = pos - (float)js;                     // [0, 3]
    float xm1 = x - 1.0f, xm2 = x - 2.0f, xm3 = x - 3.0f;
    float w0 = -(xm1 * xm2 * xm3) * (1.0f / 6.0f);
    float w1 =  (x   * xm2 * xm3) * 0.5f;
    float w2 = -(x   * xm1 * xm3) * 0.5f;
    float w3 =  (x   * xm1 * xm2) * (1.0f / 6.0f);
    float q = w0 * __shfl(QB, js)     + w1 * __shfl(QB, js + 1)
            + w2 * __shfl(QB, js + 2) + w3 * __shfl(QB, js + 3);
    r[u] = I0 * __expf(q - g * (pos * h));         // pos/M = (i+1)/T
  }
  if (o0 + OVPT <= T) {
    float4* o4 = (float4*)(out + o0);
    o4[0] = make_float4(r[0], r[1], r[2], r[3]);
    o4[1] = make_float4(r[4], r[5], r[6], r[7]);
  } else {
#pragma unroll
    for (int u = 0; u < OVPT; ++u) {
      int i = o0 + u;
      if (i < T) out[i] = r[u];
    }
  }
}

extern "C" void kernel_launch(void* const* d_in, const int* in_sizes, int n_in,
                              void* d_out, int out_size, void* d_ws, size_t ws_size,
                              hipStream_t stream) {
  const float* I0 = (const float*)d_in[1];
  const float* W1 = (const float*)d_in[2];
  const float* b1 = (const float*)d_in[3];
  const float* W2 = (const float*)d_in[4];
  const float* b2 = (const float*)d_in[5];
  const float* W3 = (const float*)d_in[6];
  const float* b3 = (const float*)d_in[7];
  const float* gp = (const float*)d_in[8];
  float* out = (float*)d_out;
  int T = in_sizes[0];

  int blocks = (T + OTILE - 1) / OTILE;            // 245
  hipLaunchKernelGGL(sir_fused_kernel, dim3(blocks), dim3(TPB), 0, stream,
                     I0, W1, b1, W2, b2, W3, b3, gp, out, T);
}

// Round 5
// 25.802 us; speedup vs baseline: 1.1149x; 1.1149x over previous
//
#include <hip/hip_runtime.h>

static constexpr int HID = 64;
static constexpr int M   = 63;            // intervals; knots 0..63 = one wave
static constexpr int NK  = 64;
static constexpr int TPB = 256;
static constexpr int OVPT  = 8;           // outputs per thread
static constexpr int OTILE = TPB * OVPT;  // 2048 outputs per block

__device__ __forceinline__ float softplusf(float x) {
  return (x > 20.0f) ? x : log1pf(expf(x));
}

// fast tanh via hardware exp + rcp: tanh(x) = 1 - 2/(e^{2x}+1).
// |rel err| ~1e-7 (v_exp/v_rcp are ~1ulp); overflow/underflow saturate correctly.
__device__ __forceinline__ float fast_tanhf(float x) {
  float e = __expf(2.0f * x);
  return 1.0f - 2.0f * __builtin_amdgcn_rcpf(e + 1.0f);
}

// Single fused kernel; every block redundantly computes the 64-knot solution
// (identical fp32 work -> deterministic), then writes its own output slice.
//  1. beta = softplus(MLP(t)) at 64 knots. Layer-2 GEMM register-double-buffers
//     W2 (16 float4 in flight) so L2 latency pipelines instead of serializing.
//  2. 7 Picard half-passes of the SIR integral equations in one wave's
//     registers (lane p = knot p), 4th-order cumulative quadrature.
//  3. cubic-Lagrange interp of Q_I + exp, 8 outputs/thread, float4 stores.
__global__ void __launch_bounds__(TPB, 1)
sir_fused_kernel(const float* __restrict__ I_init,
                 const float* __restrict__ W1, const float* __restrict__ b1,
                 const float* __restrict__ W2, const float* __restrict__ b2,
                 const float* __restrict__ W3, const float* __restrict__ b3,
                 const float* __restrict__ gamma_param,
                 float* __restrict__ out, int T) {
  __shared__ float h1T[HID * NK];   // [unit][knot], 16 KB
  __shared__ float beta_s[NK];

  const int tid  = threadIdx.x;
  const int lane = tid & 63;
  const int wid  = tid >> 6;

  const float I0 = I_init[0];
  const float S0 = 1.0f - I0;
  const float g  = softplusf(gamma_param[0]);
  const float h  = 1.0f / (float)M;

  // ---- layer 1: h1T[unit][knot] = tanh(t_knot * W1[unit] + b1[unit]) ----
  {
    float u = (float)lane * h;                    // knot = lane
#pragma unroll
    for (int r = 0; r < 16; ++r) {
      int unit = r * 4 + wid;                     // wave-uniform unit
      h1T[unit * NK + lane] = fast_tanhf(fmaf(u, W1[unit], b1[unit]));
    }
  }

  // ---- layers 2+3: thread -> (knot = tid>>2, 16 units j0..j0+15) ----
  const int knot = tid >> 2;
  const int q    = tid & 3;
  const int j0   = q * 16;
  const float* W2b = W2 + j0;

  float z2[16];
#pragma unroll
  for (int c = 0; c < 4; ++c) {
    float4 b = *(const float4*)(b2 + j0 + 4 * c);
    z2[4*c+0] = b.x; z2[4*c+1] = b.y; z2[4*c+2] = b.z; z2[4*c+3] = b.w;
  }

  // prefetch chunk 0 (k = 0..3) BEFORE the barrier: hides L2 latency under it
  float4 bufA[16], bufB[16];
#pragma unroll
  for (int r = 0; r < 16; ++r)
    bufA[r] = *(const float4*)(W2b + (r >> 2) * HID + (r & 3) * 4);

  __syncthreads();   // h1T ready

#pragma unroll
  for (int kc = 0; kc < HID; kc += 8) {
    // prefetch k = kc+4..kc+7 into bufB, then compute k = kc..kc+3 from bufA
#pragma unroll
    for (int r = 0; r < 16; ++r)
      bufB[r] = *(const float4*)(W2b + (kc + 4 + (r >> 2)) * HID + (r & 3) * 4);
#pragma unroll
    for (int kk = 0; kk < 4; ++kk) {
      float hk = h1T[(kc + kk) * NK + knot];      // broadcast, conflict-free
#pragma unroll
      for (int c = 0; c < 4; ++c) {
        float4 w = bufA[kk * 4 + c];
        z2[4*c+0] = fmaf(hk, w.x, z2[4*c+0]);
        z2[4*c+1] = fmaf(hk, w.y, z2[4*c+1]);
        z2[4*c+2] = fmaf(hk, w.z, z2[4*c+2]);
        z2[4*c+3] = fmaf(hk, w.w, z2[4*c+3]);
      }
    }
    // prefetch k = kc+8..kc+11 into bufA, compute k = kc+4..kc+7 from bufB
    if (kc + 8 < HID) {
#pragma unroll
      for (int r = 0; r < 16; ++r)
        bufA[r] = *(const float4*)(W2b + (kc + 8 + (r >> 2)) * HID + (r & 3) * 4);
    }
#pragma unroll
    for (int kk = 0; kk < 4; ++kk) {
      float hk = h1T[(kc + 4 + kk) * NK + knot];
#pragma unroll
      for (int c = 0; c < 4; ++c) {
        float4 w = bufB[kk * 4 + c];
        z2[4*c+0] = fmaf(hk, w.x, z2[4*c+0]);
        z2[4*c+1] = fmaf(hk, w.y, z2[4*c+1]);
        z2[4*c+2] = fmaf(hk, w.z, z2[4*c+2]);
        z2[4*c+3] = fmaf(hk, w.w, z2[4*c+3]);
      }
    }
  }

  {
    float acc = 0.0f;
#pragma unroll
    for (int jj = 0; jj < 16; ++jj)
      acc = fmaf(fast_tanhf(z2[jj]), W3[j0 + jj], acc);
    acc += __shfl_xor(acc, 1);
    acc += __shfl_xor(acc, 2);
    if (q == 0) beta_s[knot] = softplusf(acc + b3[0]);
  }
  __syncthreads();

  // ---- Picard: lane p = knot p; 7 half-passes, all in registers ----
  const int p = lane;
  const float tp = (float)p * h;
  const float bet = beta_s[p];
  const float c24 = h * (1.0f / 24.0f);
  float QA = 0.0f, QB = 0.0f;
  const int im2 = p >= 2 ? p - 2 : 0;
  const int im1 = p >= 1 ? p - 1 : 0;
  const int ip1 = p <= 62 ? p + 1 : 63;
  const int ip2 = p <= 61 ? p + 2 : 63;
  const int ip3 = p <= 60 ? p + 3 : 63;
#pragma unroll
  for (int ph = 0; ph < 7; ++ph) {
    const bool iPass = (ph & 1) == 0;
    float f = iPass ? (bet * S0 * __expf(-QA))
                    : (bet * I0 * __expf(QB - g * tp));
    float fm2 = __shfl(f, im2);
    float fm1 = __shfl(f, im1);
    float f1  = __shfl(f, ip1);
    float f2  = __shfl(f, ip2);
    float f3  = __shfl(f, ip3);
    float e;
    if (p == 0)       e = 9.0f*f + 19.0f*f1 - 5.0f*f2 + f3;     // AM start
    else if (p < 62)  e = 13.0f*(f + f1) - fm1 - f2;            // interior
    else if (p == 62) e = fm2 - 5.0f*fm1 + 19.0f*f + 9.0f*f1;   // AM end
    else              e = 0.0f;                                 // lane 63
    e *= c24;
    float incl = e;
#pragma unroll
    for (int off = 1; off < 64; off <<= 1) {
      float w = __shfl_up(incl, off);
      if (lane >= off) incl += w;
    }
    float Q = incl - e;                    // exclusive prefix = Q at knot p
    if (iPass) QB = Q; else QA = Q;
  }
  // QB (I-exponent) now lives in each wave's lanes.

  // ---- output slice: cubic-Lagrange interp of QB via lane-indexed shfl ----
  const float scale = (float)M / (float)T;
  int o0 = blockIdx.x * OTILE + tid * OVPT;
  float r[OVPT];
#pragma unroll
  for (int u = 0; u < OVPT; ++u) {
    int i = o0 + u;
    float pos = (float)(i + 1) * scale;            // (0, M]
    int js = (int)pos - 1;
    js = js < 0 ? 0 : (js > M - 3 ? M - 3 : js);   // [0, 60]
    float x = pos - (float)js;                     // [0, 3]
    float xm1 = x - 1.0f, xm2 = x - 2.0f, xm3 = x - 3.0f;
    float w0 = -(xm1 * xm2 * xm3) * (1.0f / 6.0f);
    float w1 =  (x   * xm2 * xm3) * 0.5f;
    float w2 = -(x   * xm1 * xm3) * 0.5f;
    float w3 =  (x   * xm1 * xm2) * (1.0f / 6.0f);
    float qv = w0 * __shfl(QB, js)     + w1 * __shfl(QB, js + 1)
             + w2 * __shfl(QB, js + 2) + w3 * __shfl(QB, js + 3);
    r[u] = I0 * __expf(qv - g * (pos * h));        // pos/M = (i+1)/T
  }
  if (o0 + OVPT <= T) {
    float4* o4 = (float4*)(out + o0);
    o4[0] = make_float4(r[0], r[1], r[2], r[3]);
    o4[1] = make_float4(r[4], r[5], r[6], r[7]);
  } else {
#pragma unroll
    for (int u = 0; u < OVPT; ++u) {
      int i = o0 + u;
      if (i < T) out[i] = r[u];
    }
  }
}

extern "C" void kernel_launch(void* const* d_in, const int* in_sizes, int n_in,
                              void* d_out, int out_size, void* d_ws, size_t ws_size,
                              hipStream_t stream) {
  const float* I0 = (const float*)d_in[1];
  const float* W1 = (const float*)d_in[2];
  const float* b1 = (const float*)d_in[3];
  const float* W2 = (const float*)d_in[4];
  const float* b2 = (const float*)d_in[5];
  const float* W3 = (const float*)d_in[6];
  const float* b3 = (const float*)d_in[7];
  const float* gp = (const float*)d_in[8];
  float* out = (float*)d_out;
  int T = in_sizes[0];

  int blocks = (T + OTILE - 1) / OTILE;            // 245
  hipLaunchKernelGGL(sir_fused_kernel, dim3(blocks), dim3(TPB), 0, stream,
                     I0, W1, b1, W2, b2, W3, b3, gp, out, T);
}

// Round 6
// 16.299 us; speedup vs baseline: 1.7650x; 1.5830x over previous
//
#include <hip/hip_runtime.h>

static constexpr int HID = 64;
static constexpr int M   = 63;            // intervals; knots 0..63 = one wave
static constexpr int NK  = 64;
static constexpr int OVPT  = 4;           // outputs per thread (K2)
static constexpr int OTPB  = 256;
static constexpr int OTILE = OTPB * OVPT; // 1024 outputs per block

__device__ __forceinline__ float softplusf(float x) {
  return (x > 20.0f) ? x : log1pf(expf(x));
}

// fast tanh via hardware exp + rcp: tanh(x) = 1 - 2/(e^{2x}+1). rel err ~1e-7.
__device__ __forceinline__ float fast_tanhf(float x) {
  float e = __expf(2.0f * x);
  return 1.0f - 2.0f * __builtin_amdgcn_rcpf(e + 1.0f);
}

// ---------------- K1: one block computes qg[64] ----------------
//  1. stage W2 (16 KB) into LDS: 1024 threads x one float4 -> one fully
//     parallel HBM round instead of a serialized per-thread miss chain.
//  2. h1T[k][knot] = tanh(t_knot*W1[k]+b1[k])  (4 values/thread).
//  3. layer2+3: thread -> (knot = tid>>4, 4 units j0=4*(tid&15)); k-loop
//     reads are LDS broadcasts (conflict-free); 16-lane shfl_xor reduce.
//  4. wave 0: 7 Picard half-passes in registers (lane p = knot p, 4th-order
//     cumulative quadrature), writes qg[p] = Q_I(t_p) - g*t_p.
__global__ void __launch_bounds__(1024)
knots_picard_kernel(const float* __restrict__ I_init,
                    const float* __restrict__ W1, const float* __restrict__ b1,
                    const float* __restrict__ W2, const float* __restrict__ b2,
                    const float* __restrict__ W3, const float* __restrict__ b3,
                    const float* __restrict__ gamma_param,
                    float* __restrict__ qg_out) {
  __shared__ float W2s[HID * HID];   // 16 KB
  __shared__ float h1T[HID * NK];    // 16 KB, [k][knot]
  __shared__ float beta_s[NK];

  const int tid = threadIdx.x;
  const float h = 1.0f / (float)M;

  // stage W2: one coalesced float4 per thread (4096 floats total)
  ((float4*)W2s)[tid] = ((const float4*)W2)[tid];

  // h1T: idx = r*1024+tid -> k = idx>>6 (wave-uniform), knot = idx&63 (=lane)
#pragma unroll
  for (int r = 0; r < 4; ++r) {
    int idx = r * 1024 + tid;
    int k = idx >> 6;
    int knot = idx & 63;
    h1T[k * NK + knot] = fast_tanhf(fmaf((float)knot * h, W1[k], b1[k]));
  }
  __syncthreads();

  // layers 2+3
  {
    const int knot = tid >> 4;
    const int jq   = tid & 15;
    const int j0   = jq * 4;
    float4 bb = *(const float4*)(b2 + j0);
    float z0 = bb.x, z1 = bb.y, z2 = bb.z, z3 = bb.w;
#pragma unroll 8
    for (int k = 0; k < HID; ++k) {
      float hk = h1T[k * NK + knot];                 // broadcast
      float4 w = *(const float4*)(W2s + k * HID + j0); // b128, same-addr x4
      z0 = fmaf(hk, w.x, z0); z1 = fmaf(hk, w.y, z1);
      z2 = fmaf(hk, w.z, z2); z3 = fmaf(hk, w.w, z3);
    }
    float4 w3v = *(const float4*)(W3 + j0);
    float acc = fast_tanhf(z0) * w3v.x + fast_tanhf(z1) * w3v.y
              + fast_tanhf(z2) * w3v.z + fast_tanhf(z3) * w3v.w;
    acc += __shfl_xor(acc, 1);
    acc += __shfl_xor(acc, 2);
    acc += __shfl_xor(acc, 4);
    acc += __shfl_xor(acc, 8);
    if (jq == 0) beta_s[knot] = softplusf(acc + b3[0]);
  }
  __syncthreads();

  if (tid >= 64) return;   // picard on wave 0 only

  const float I0 = I_init[0];
  const float S0 = 1.0f - I0;
  const float g  = softplusf(gamma_param[0]);

  const int p = tid;
  const float tp = (float)p * h;
  const float bet = beta_s[p];
  const float c24 = h * (1.0f / 24.0f);
  float QA = 0.0f, QB = 0.0f;
  const int im2 = p >= 2 ? p - 2 : 0;
  const int im1 = p >= 1 ? p - 1 : 0;
  const int ip1 = p <= 62 ? p + 1 : 63;
  const int ip2 = p <= 61 ? p + 2 : 63;
  const int ip3 = p <= 60 ? p + 3 : 63;
#pragma unroll
  for (int ph = 0; ph < 7; ++ph) {
    const bool iPass = (ph & 1) == 0;
    float f = iPass ? (bet * S0 * __expf(-QA))
                    : (bet * I0 * __expf(QB - g * tp));
    float fm2 = __shfl(f, im2);
    float fm1 = __shfl(f, im1);
    float f1  = __shfl(f, ip1);
    float f2  = __shfl(f, ip2);
    float f3  = __shfl(f, ip3);
    float e;
    if (p == 0)       e = 9.0f*f + 19.0f*f1 - 5.0f*f2 + f3;     // AM start
    else if (p < 62)  e = 13.0f*(f + f1) - fm1 - f2;            // interior
    else if (p == 62) e = fm2 - 5.0f*fm1 + 19.0f*f + 9.0f*f1;   // AM end
    else              e = 0.0f;                                 // lane 63
    e *= c24;
    float incl = e;
#pragma unroll
    for (int off = 1; off < 64; off <<= 1) {
      float w = __shfl_up(incl, off);
      if (p >= off) incl += w;
    }
    float Q = incl - e;                    // exclusive prefix = Q at knot p
    if (iPass) QB = Q; else QA = Q;
  }
  qg_out[p] = QB - g * tp;   // fold linear term: exact under cubic interp
}

// ---------------- K2: pure output ----------------
// out[i] = I0 * exp(cubic_interp(qg, (i+1)*M/T)); qg table in LDS.
__global__ void __launch_bounds__(OTPB)
output_kernel(const float* __restrict__ qg, const float* __restrict__ I_init,
              float* __restrict__ out, int T) {
  __shared__ float q_lds[NK];
  const int tid = threadIdx.x;
  if (tid < NK) q_lds[tid] = qg[tid];
  __syncthreads();

  const float I0 = I_init[0];
  const float scale = (float)M / (float)T;
  int o0 = blockIdx.x * OTILE + tid * OVPT;
  float r[OVPT];
#pragma unroll
  for (int u = 0; u < OVPT; ++u) {
    int i = o0 + u;
    float pos = (float)(i + 1) * scale;            // (0, M]
    int js = (int)pos - 1;
    js = js < 0 ? 0 : (js > M - 3 ? M - 3 : js);   // [0, 60]
    float x = pos - (float)js;                     // [0, 3]
    float xm1 = x - 1.0f, xm2 = x - 2.0f, xm3 = x - 3.0f;
    float w0 = -(xm1 * xm2 * xm3) * (1.0f / 6.0f);
    float w1 =  (x   * xm2 * xm3) * 0.5f;
    float w2 = -(x   * xm1 * xm3) * 0.5f;
    float w3 =  (x   * xm1 * xm2) * (1.0f / 6.0f);
    float qv = w0 * q_lds[js]     + w1 * q_lds[js + 1]
             + w2 * q_lds[js + 2] + w3 * q_lds[js + 3];
    r[u] = I0 * __expf(qv);
  }
  if (o0 + OVPT <= T) {
    *(float4*)(out + o0) = make_float4(r[0], r[1], r[2], r[3]);
  } else {
#pragma unroll
    for (int u = 0; u < OVPT; ++u) {
      int i = o0 + u;
      if (i < T) out[i] = r[u];
    }
  }
}

extern "C" void kernel_launch(void* const* d_in, const int* in_sizes, int n_in,
                              void* d_out, int out_size, void* d_ws, size_t ws_size,
                              hipStream_t stream) {
  const float* I0 = (const float*)d_in[1];
  const float* W1 = (const float*)d_in[2];
  const float* b1 = (const float*)d_in[3];
  const float* W2 = (const float*)d_in[4];
  const float* b2 = (const float*)d_in[5];
  const float* W3 = (const float*)d_in[6];
  const float* b3 = (const float*)d_in[7];
  const float* gp = (const float*)d_in[8];
  float* out = (float*)d_out;
  int T = in_sizes[0];

  float* qg = (float*)d_ws;                        // [NK]

  hipLaunchKernelGGL(knots_picard_kernel, dim3(1), dim3(1024), 0, stream,
                     I0, W1, b1, W2, b2, W3, b3, gp, qg);

  int blocks = (T + OTILE - 1) / OTILE;            // 489
  hipLaunchKernelGGL(output_kernel, dim3(blocks), dim3(OTPB), 0, stream,
                     qg, I0, out, T);
}